// Round 11
// baseline (173.013 us; speedup 1.0000x reference)
//
#include <hip/hip_runtime.h>
#include <hip/hip_bf16.h>
#include <cstdint>
#include <cstddef>

// Problem constants
#define B_ 8
#define S_ 2048
#define D_ 1024
#define RFAC 32.0f
#define ALPHA 0.2f
#define BETA 0.1f
#define GAMMA 0.1f
// EMA truncation window: 0.8^32 ~ 8e-4 (threshold 0.108)
#define KW 32
#define TB 64

typedef float f32x4_t __attribute__((ext_vector_type(4)));
typedef short bf16x8_t __attribute__((ext_vector_type(8)));

__device__ __forceinline__ unsigned short f2bf(float f) {
    unsigned u = __float_as_uint(f);
    u = (u + 0x7fffu + ((u >> 16) & 1u)) >> 16;
    return (unsigned short)u;
}
__device__ __forceinline__ unsigned cvtpk(float lo, float hi) {
    unsigned r;
    asm("v_cvt_pk_bf16_f32 %0, %1, %2" : "=v"(r) : "v"(lo), "v"(hi));
    return r;
}

// ---------------------------------------------------------------------------
// Kernel 1: W -> bf16 convert.
__global__ __launch_bounds__(256) void wconv_k(const float* __restrict__ W,
                                               unsigned short* __restrict__ Wb) {
    int i = blockIdx.x * 256 + threadIdx.x;
    float4 w = ((const float4*)W)[i];
    ushort4 o;
    o.x = f2bf(w.x); o.y = f2bf(w.y); o.z = f2bf(w.z); o.w = f2bf(w.w);
    ((ushort4*)Wb)[i] = o;
}

// ---------------------------------------------------------------------------
// Kernel 2: fused norm+EMA+coef, ONE WAVE PER (b,chunk) TASK — zero LDS,
// zero barriers (R8-R10 lesson: any per-t block barrier = 100us lockstep).
// Lane l owns d in {4l + 256i : i=0..3} (all loads/stores unit-stride).
// Row norm = 6-step in-wave shfl_xor butterfly, pipelined NS=2 ahead of the
// EMA recurrence (which is 1 FMA/t). uu/sd butterfly is a dead-end branch.
// Ring depth 4 on q,k,v: 48 vmem in flight (<63 vmcnt limit); grid=256
// 1-wave blocks -> 256 CUs x 48KB in flight = 12MB >> BW*latency (2.4MB).
// launch_bounds(64,1): 1 wave/SIMD target, VGPR cap 512 -> no spill at ~250.
__global__ __launch_bounds__(64, 1) void ema_fused_k(const float* __restrict__ q,
                                                     const float* __restrict__ kk,
                                                     const float* __restrict__ vv,
                                                     unsigned short* __restrict__ Ub,
                                                     float* __restrict__ coef) {
    int lane = threadIdx.x;
    int b = blockIdx.x >> 5;           // 32 chunks per b
    int chunk = blockIdx.x & 31;
    int t0 = chunk * TB;
    int ts = t0 - KW; if (ts < 0) ts = 0;
    const int tend = t0 + TB;
    const float4* qb = (const float4*)(q  + (size_t)b * S_ * D_) + lane;
    const float4* kb = (const float4*)(kk + (size_t)b * S_ * D_) + lane;
    const float4* vb = (const float4*)(vv + (size_t)b * S_ * D_) + lane;
    // float4 index for (t, i): t*256 + i*64

    float4 rq[4][4], rk[4][4], rv[4][4];
    float nqs[4], nks[4];

    // ---- pipeline fill: slots j hold times ts+j ----
#pragma unroll
    for (int j = 0; j < 4; ++j) {
        size_t o = (size_t)(ts + j) * 256;
#pragma unroll
        for (int i = 0; i < 4; ++i) { rq[j][i] = qb[o + i * 64]; rk[j][i] = kb[o + i * 64]; }
        if (ts + j >= t0) {
#pragma unroll
            for (int i = 0; i < 4; ++i) rv[j][i] = vb[o + i * 64];
        }
    }
    // norms for ts, ts+1 (slots 0,1)
#pragma unroll
    for (int m = 0; m < 2; ++m) {
        float sq = 0.f, sk = 0.f;
#pragma unroll
        for (int i = 0; i < 4; ++i) {
            sq += rq[m][i].x*rq[m][i].x + rq[m][i].y*rq[m][i].y + rq[m][i].z*rq[m][i].z + rq[m][i].w*rq[m][i].w;
            sk += rk[m][i].x*rk[m][i].x + rk[m][i].y*rk[m][i].y + rk[m][i].z*rk[m][i].z + rk[m][i].w*rk[m][i].w;
        }
#pragma unroll
        for (int off = 32; off > 0; off >>= 1) {
            sq += __shfl_xor(sq, off, 64);
            sk += __shfl_xor(sk, off, 64);
        }
        nqs[m] = sq; nks[m] = sk;
    }

    float4 u4[4], v4[4];
#pragma unroll
    for (int i = 0; i < 4; ++i) {
        u4[i] = (float4){0.f,0.f,0.f,0.f};
        v4[i] = (float4){0.f,0.f,0.f,0.f};
    }
    const float om = 1.f - ALPHA;
    const int NI = tend - ts;          // 64 or 96, both % 4 == 0
    for (int g = 0; g < NI; g += 4) {
#pragma unroll
        for (int j = 0; j < 4; ++j) {
            int t = ts + g + j;
            // ---- lookahead norm for t+2 (slot (j+2)&3; data loaded 2 iters ago;
            //      result consumed 2 iterations later -> butterfly off-chain) ----
            if (t + 2 < tend) {
                const int s = (j + 2) & 3;
                float sq = 0.f, sk = 0.f;
#pragma unroll
                for (int i = 0; i < 4; ++i) {
                    sq += rq[s][i].x*rq[s][i].x + rq[s][i].y*rq[s][i].y + rq[s][i].z*rq[s][i].z + rq[s][i].w*rq[s][i].w;
                    sk += rk[s][i].x*rk[s][i].x + rk[s][i].y*rk[s][i].y + rk[s][i].z*rk[s][i].z + rk[s][i].w*rk[s][i].w;
                }
#pragma unroll
                for (int off = 32; off > 0; off >>= 1) {
                    sq += __shfl_xor(sq, off, 64);
                    sk += __shfl_xor(sk, off, 64);
                }
                nqs[s] = sq; nks[s] = sk;
            }
            // ---- EMA update (the only true recurrence: 1 FMA per element) ----
            float aq = ALPHA / (sqrtf(nqs[j]) + 1e-6f);
            float ak = ALPHA / (sqrtf(nks[j]) + 1e-6f);
#pragma unroll
            for (int i = 0; i < 4; ++i) {
                u4[i].x = om*u4[i].x + aq*rq[j][i].x; u4[i].y = om*u4[i].y + aq*rq[j][i].y;
                u4[i].z = om*u4[i].z + aq*rq[j][i].z; u4[i].w = om*u4[i].w + aq*rq[j][i].w;
                v4[i].x = om*v4[i].x + ak*rk[j][i].x; v4[i].y = om*v4[i].y + ak*rk[j][i].y;
                v4[i].z = om*v4[i].z + ak*rk[j][i].z; v4[i].w = om*v4[i].w + ak*rk[j][i].w;
            }
            // ---- output region: coef (dead-end butterfly) + Ub bf16 store ----
            if (t >= t0) {
                float uu = 0.f, sd = 0.f;
#pragma unroll
                for (int i = 0; i < 4; ++i) {
                    uu += u4[i].x*u4[i].x + u4[i].y*u4[i].y + u4[i].z*u4[i].z + u4[i].w*u4[i].w;
                    sd += v4[i].x*rv[j][i].x + v4[i].y*rv[j][i].y + v4[i].z*rv[j][i].z + v4[i].w*rv[j][i].w;
                }
#pragma unroll
                for (int off = 32; off > 0; off >>= 1) {
                    uu += __shfl_xor(uu, off, 64);
                    sd += __shfl_xor(sd, off, 64);
                }
                if (lane == 0) {
                    float nrm = RFAC * fabsf(sd) * sqrtf(uu);
                    float n = fmaxf(nrm, 1e-6f);
                    coef[b * S_ + t] = GAMMA * RFAC * sd / (1.f + BETA * (n - 1.f));
                }
                unsigned short* ur = Ub + (size_t)(b * S_ + t) * D_ + lane * 4;
#pragma unroll
                for (int i = 0; i < 4; ++i) {
                    uint2 rr;
                    rr.x = cvtpk(u4[i].x, u4[i].y);
                    rr.y = cvtpk(u4[i].z, u4[i].w);
                    *(uint2*)(ur + i * 256) = rr;
                }
            }
            // ---- prefetch t+4 into slot j (clamped; dup loads harmless) ----
            int tf = t + 4;
            int tc = tf < tend ? tf : tend - 1;
            size_t o = (size_t)tc * 256;
#pragma unroll
            for (int i = 0; i < 4; ++i) { rq[j][i] = qb[o + i * 64]; rk[j][i] = kb[o + i * 64]; }
            if (tf >= t0 && tf < tend) {
#pragma unroll
                for (int i = 0; i < 4; ++i) rv[j][i] = vb[o + i * 64];
            }
        }
    }
}

// ---------------------------------------------------------------------------
// Kernel 3: out[m,n] = x[m,n] + coef[m] * sum_d U[m,d] * W[n,d]
// 128x128 tile, BK=64, 4 waves (2x2), double-buffered 64KB LDS -> 2
// blocks/CU, grid 1024. Counted vmcnt 2-deep pipeline; XOR chunk swizzle.
// Measured ~37us — unchanged.
#define BM 128
#define BN 128
#define BK 64
#define NT (D_ / BK)   // 16 K-tiles

__global__ __launch_bounds__(256) void gemm_k(const unsigned short* __restrict__ A,   // M x K bf16
                                              const unsigned short* __restrict__ Bw,  // N x K bf16
                                              const float* __restrict__ coef,
                                              const float* __restrict__ x,
                                              float* __restrict__ out) {
    const int N = D_, K = D_;
    __shared__ unsigned short lds[2 * 2 * BM * BK];   // [buf][A|B], 64 KiB
    int bid = blockIdx.x;
    int swz = (bid & 7) * 128 + (bid >> 3);  // 1024 % 8 == 0: bijective XCD remap
    int tm = swz >> 3, tn = swz & 7;         // 128 M-tiles, 8 N-tiles
    int m0 = tm * BM, n0 = tn * BN;
    int tid = threadIdx.x;
    int lane = tid & 63;
    int wid = tid >> 6;
    int wr = wid >> 1, wc = wid & 1;         // 2x2 wave grid; wave tile 64x64
    int lr = lane & 15, lg = lane >> 4;

    f32x4_t acc[4][4];
#pragma unroll
    for (int i = 0; i < 4; ++i)
#pragma unroll
        for (int j = 0; j < 4; ++j)
            acc[i][j] = (f32x4_t){0.f, 0.f, 0.f, 0.f};

#define STAGE_MAT(buf, kt, isB)                                                       \
    {                                                                                 \
        const unsigned short* Gp =                                                    \
            ((isB) ? Bw + (size_t)n0 * K : A + (size_t)m0 * K) + (size_t)(kt) * BK;   \
        char* Lp = (char*)lds + (buf) * 32768 + (isB) * 16384;                        \
        _Pragma("unroll")                                                             \
        for (int i = 0; i < 4; ++i) {                                                 \
            int c = i * 256 + tid;                                                    \
            int row = c >> 3, cl = c & 7;                                             \
            int gc = cl ^ (row & 7);          /* pre-swizzled global chunk */         \
            __builtin_amdgcn_global_load_lds(                                         \
                (const __attribute__((address_space(1))) void*)(Gp + (size_t)row * K + gc * 8), \
                (__attribute__((address_space(3))) void*)(Lp + c * 16), 16, 0, 0);    \
        }                                                                             \
    }
#define STAGE_TILE(buf, kt) STAGE_MAT(buf, kt, 0) STAGE_MAT(buf, kt, 1)

    STAGE_TILE(0, 0);
    STAGE_TILE(1, 1);

    for (int t = 0; t < NT; ++t) {
        if (t == NT - 1) asm volatile("s_waitcnt vmcnt(0)" ::: "memory");
        else             asm volatile("s_waitcnt vmcnt(8)" ::: "memory");
        __builtin_amdgcn_s_barrier();
        const unsigned short* La = lds + (t & 1) * 16384;
        const unsigned short* Lb = La + 8192;
        bf16x8_t af[4][2], bf[4][2];
#pragma unroll
        for (int kkk = 0; kkk < 2; ++kkk) {
#pragma unroll
            for (int mi = 0; mi < 4; ++mi) {
                int row = wr * 64 + mi * 16 + lr;
                int ch = (kkk * 4 + lg) ^ (row & 7);
                af[mi][kkk] = *(const bf16x8_t*)(La + (row * 8 + ch) * 8);
            }
#pragma unroll
            for (int ni = 0; ni < 4; ++ni) {
                int row = wc * 64 + ni * 16 + lr;
                int ch = (kkk * 4 + lg) ^ (row & 7);
                bf[ni][kkk] = *(const bf16x8_t*)(Lb + (row * 8 + ch) * 8);
            }
        }
        asm volatile("s_waitcnt lgkmcnt(0)" ::: "memory");
        __builtin_amdgcn_sched_barrier(0);
        __builtin_amdgcn_s_setprio(1);
#pragma unroll
        for (int kkk = 0; kkk < 2; ++kkk)
#pragma unroll
            for (int mi = 0; mi < 4; ++mi)
#pragma unroll
                for (int ni = 0; ni < 4; ++ni)
                    acc[mi][ni] = __builtin_amdgcn_mfma_f32_16x16x32_bf16(
                        af[mi][kkk], bf[ni][kkk], acc[mi][ni], 0, 0, 0);
        __builtin_amdgcn_s_setprio(0);
        __builtin_amdgcn_s_barrier();
        if (t + 2 < NT) { STAGE_TILE((t & 1), t + 2); }
    }
#undef STAGE_TILE
#undef STAGE_MAT

#pragma unroll
    for (int mi = 0; mi < 4; ++mi) {
#pragma unroll
        for (int i = 0; i < 4; ++i) {
            int m = m0 + wr * 64 + mi * 16 + lg * 4 + i;
            float cf = coef[m];
#pragma unroll
            for (int ni = 0; ni < 4; ++ni) {
                int n = n0 + wc * 64 + ni * 16 + lr;
                size_t idx = (size_t)m * N + n;
                out[idx] = x[idx] + cf * acc[mi][ni][i];
            }
        }
    }
}

// ---------------------------------------------------------------------------
extern "C" void kernel_launch(void* const* d_in, const int* in_sizes, int n_in,
                              void* d_out, int out_size, void* d_ws, size_t ws_size,
                              hipStream_t stream) {
    const float* x  = (const float*)d_in[0];
    const float* q  = (const float*)d_in[1];
    const float* k  = (const float*)d_in[2];
    const float* vv = (const float*)d_in[3];
    const float* W  = (const float*)d_in[4];
    float* out = (float*)d_out;

    const size_t M = (size_t)B_ * S_;           // 16384
    char* ws = (char*)d_ws;
    unsigned short* Ub = (unsigned short*)ws;                      // 32MB
    unsigned short* Wb = (unsigned short*)(ws + M * D_ * 2);       // 2MB
    float* coef = (float*)(ws + M * D_ * 2 + (size_t)D_ * D_ * 2);
    size_t needed = M * D_ * 2 + (size_t)D_ * D_ * 2 + M * 4;
    if (ws_size < needed) return;  // fail visibly (output stays poisoned)

    wconv_k<<<dim3((D_ * D_) / 1024), dim3(256), 0, stream>>>(W, Wb);
    ema_fused_k<<<dim3(B_ * (S_ / TB)), dim3(64), 0, stream>>>(q, k, vv, Ub, coef);
    gemm_k<<<dim3((M / BM) * (D_ / BN)), dim3(256), 0, stream>>>(Ub, Wb, coef, x, out);
}

// Round 12
// 127.177 us; speedup vs baseline: 1.3604x; 1.3604x over previous
//
#include <hip/hip_runtime.h>
#include <hip/hip_bf16.h>
#include <cstdint>
#include <cstddef>

// Problem constants
#define B_ 8
#define S_ 2048
#define D_ 1024
#define RFAC 32.0f
#define ALPHA 0.2f
#define BETA 0.1f
#define GAMMA 0.1f
// EMA truncation window: 0.8^32 ~ 8e-4 (threshold 0.108)
#define KW 32
#define TB 64
#define PF_ 8   // ema prefetch pipeline depth (static ring, fully unrolled)

typedef float f32x4_t __attribute__((ext_vector_type(4)));
typedef short bf16x8_t __attribute__((ext_vector_type(8)));

__device__ __forceinline__ unsigned short f2bf(float f) {
    unsigned u = __float_as_uint(f);
    u = (u + 0x7fffu + ((u >> 16) & 1u)) >> 16;
    return (unsigned short)u;
}

// ---------------------------------------------------------------------------
// Kernel 1: per-row reciprocal norms (pre-scaled by ALPHA). One wave per row.
// Measured ~28us (R7).
__global__ __launch_bounds__(256) void norms_k(const float* __restrict__ q,
                                               const float* __restrict__ k,
                                               float* __restrict__ rnq,
                                               float* __restrict__ rnk) {
    int row  = blockIdx.x * 4 + (threadIdx.x >> 6);
    int lane = threadIdx.x & 63;
    const float4* qr = (const float4*)(q + (size_t)row * D_);
    const float4* kr = (const float4*)(k + (size_t)row * D_);
    float sq = 0.f, sk = 0.f;
#pragma unroll
    for (int j = 0; j < 4; ++j) {
        float4 a = qr[lane + 64 * j];
        float4 b = kr[lane + 64 * j];
        sq += a.x * a.x + a.y * a.y + a.z * a.z + a.w * a.w;
        sk += b.x * b.x + b.y * b.y + b.z * b.z + b.w * b.w;
    }
#pragma unroll
    for (int off = 32; off > 0; off >>= 1) {
        sq += __shfl_xor(sq, off, 64);
        sk += __shfl_xor(sk, off, 64);
    }
    if (lane == 0) {
        rnq[row] = ALPHA / (sqrtf(sq) + 1e-6f);
        rnk[row] = ALPHA / (sqrtf(sk) + 1e-6f);
    }
}

// ---------------------------------------------------------------------------
// Kernel 2: W -> bf16 convert.
__global__ __launch_bounds__(256) void wconv_k(const float* __restrict__ W,
                                               unsigned short* __restrict__ Wb) {
    int i = blockIdx.x * 256 + threadIdx.x;
    float4 w = ((const float4*)W)[i];
    ushort4 o;
    o.x = f2bf(w.x); o.y = f2bf(w.y); o.z = f2bf(w.z); o.w = f2bf(w.w);
    ((ushort4*)Wb)[i] = o;
}

// ---------------------------------------------------------------------------
// Kernel 3: windowed EMA + coef, software-pipelined (PF_=8 ring), reading
// q,k as f32 (L3-hot after norms_k) + per-row scalars rnq,rnk. Wave-local
// butterflies only; NO in-loop barriers (R8-R11 lesson). Measured ~40us (R7).
__global__ __launch_bounds__(256) void ema_coef_k(const float* __restrict__ q,
                                                  const float* __restrict__ kk,
                                                  const float* __restrict__ rnq,
                                                  const float* __restrict__ rnk,
                                                  const float* __restrict__ vv,
                                                  unsigned short* __restrict__ Ub,
                                                  float* __restrict__ coef) {
    __shared__ float sm[TB * 8];   // [t][wave*2 + {uu,sd}]
    const int chunks = S_ / TB;
    int b  = blockIdx.x / chunks;
    int t0 = (blockIdx.x % chunks) * TB;
    int ts = t0 - KW; if (ts < 0) ts = 0;
    int tid = threadIdx.x;
    int lane = tid & 63, wave = tid >> 6;
    size_t bbase = (size_t)b * S_ * D_ + tid * 4;
    const float* qp = q + bbase;
    const float* kp = kk + bbase;
    const float* vp = vv + bbase;
    unsigned short* up = Ub + bbase;
    const float* rq = rnq + b * S_;
    const float* rk = rnk + b * S_;

    float4 pq[PF_], pk[PF_], pv[PF_];
    float paq[PF_], pak[PF_];
#pragma unroll
    for (int j = 0; j < PF_; ++j) {
        size_t o = (size_t)(ts + j) * D_;
        pq[j] = *(const float4*)(qp + o);
        pk[j] = *(const float4*)(kp + o);
        paq[j] = rq[ts + j];
        pak[j] = rk[ts + j];
        if (ts + j >= t0) pv[j] = *(const float4*)(vp + o);
    }
    float u0 = 0.f, u1 = 0.f, u2 = 0.f, u3 = 0.f;
    float v0 = 0.f, v1 = 0.f, v2 = 0.f, v3 = 0.f;
    const float om = 1.f - ALPHA;
    const int NI = t0 + TB - ts;       // 64 (chunk 0) or 96; both % 8 == 0
    const int tend = t0 + TB;
    for (int g = 0; g < NI; g += PF_) {
#pragma unroll
        for (int j = 0; j < PF_; ++j) {
            int t = ts + g + j;
            float aq = paq[j], ak = pak[j];
            u0 = om * u0 + aq * pq[j].x; u1 = om * u1 + aq * pq[j].y;
            u2 = om * u2 + aq * pq[j].z; u3 = om * u3 + aq * pq[j].w;
            v0 = om * v0 + ak * pk[j].x; v1 = om * v1 + ak * pk[j].y;
            v2 = om * v2 + ak * pk[j].z; v3 = om * v3 + ak * pk[j].w;
            if (t >= t0) {               // wave-uniform branch
                float uu = u0 * u0 + u1 * u1 + u2 * u2 + u3 * u3;
                float sd = v0 * pv[j].x + v1 * pv[j].y + v2 * pv[j].z + v3 * pv[j].w;
#pragma unroll
                for (int off = 32; off > 0; off >>= 1) {
                    uu += __shfl_xor(uu, off, 64);
                    sd += __shfl_xor(sd, off, 64);
                }
                if (lane == 0) {
                    sm[(t - t0) * 8 + wave * 2 + 0] = uu;
                    sm[(t - t0) * 8 + wave * 2 + 1] = sd;
                }
                ushort4 us;
                us.x = f2bf(u0); us.y = f2bf(u1); us.z = f2bf(u2); us.w = f2bf(u3);
                *(ushort4*)(up + (size_t)t * D_) = us;
            }
            // prefetch t+PF_ into slot j (clamped; duplicate loads harmless)
            int tf = t + PF_;
            int tc = tf < tend ? tf : tend - 1;
            size_t o2 = (size_t)tc * D_;
            pq[j] = *(const float4*)(qp + o2);
            pk[j] = *(const float4*)(kp + o2);
            paq[j] = rq[tc];
            pak[j] = rk[tc];
            if (tf >= t0) pv[j] = *(const float4*)(vp + o2);
        }
    }
    __syncthreads();
    if (tid < TB) {
        float uu = sm[tid * 8 + 0] + sm[tid * 8 + 2] + sm[tid * 8 + 4] + sm[tid * 8 + 6];
        float sd = sm[tid * 8 + 1] + sm[tid * 8 + 3] + sm[tid * 8 + 5] + sm[tid * 8 + 7];
        float nrm = RFAC * fabsf(sd) * sqrtf(uu);
        float n = fmaxf(nrm, 1e-6f);
        coef[b * S_ + t0 + tid] = GAMMA * RFAC * sd / (1.f + BETA * (n - 1.f));
    }
}

// ---------------------------------------------------------------------------
// Kernel 4: out[m,n] = x[m,n] + coef[m] * sum_d U[m,d] * W[n,d]
// 128x128 tile, BK=64, 4 waves (2x2), double-buffered 64KB LDS -> 2
// blocks/CU, grid 1024. Counted vmcnt 2-deep pipeline; XOR chunk swizzle.
// Measured ~37us (R8-R10) — unchanged.
#define BM 128
#define BN 128
#define BK 64
#define NT (D_ / BK)   // 16 K-tiles

__global__ __launch_bounds__(256) void gemm_k(const unsigned short* __restrict__ A,   // M x K bf16
                                              const unsigned short* __restrict__ Bw,  // N x K bf16
                                              const float* __restrict__ coef,
                                              const float* __restrict__ x,
                                              float* __restrict__ out) {
    const int N = D_, K = D_;
    __shared__ unsigned short lds[2 * 2 * BM * BK];   // [buf][A|B], 64 KiB
    int bid = blockIdx.x;
    int swz = (bid & 7) * 128 + (bid >> 3);  // 1024 % 8 == 0: bijective XCD remap
    int tm = swz >> 3, tn = swz & 7;         // 128 M-tiles, 8 N-tiles
    int m0 = tm * BM, n0 = tn * BN;
    int tid = threadIdx.x;
    int lane = tid & 63;
    int wid = tid >> 6;
    int wr = wid >> 1, wc = wid & 1;         // 2x2 wave grid; wave tile 64x64
    int lr = lane & 15, lg = lane >> 4;

    f32x4_t acc[4][4];
#pragma unroll
    for (int i = 0; i < 4; ++i)
#pragma unroll
        for (int j = 0; j < 4; ++j)
            acc[i][j] = (f32x4_t){0.f, 0.f, 0.f, 0.f};

#define STAGE_MAT(buf, kt, isB)                                                       \
    {                                                                                 \
        const unsigned short* Gp =                                                    \
            ((isB) ? Bw + (size_t)n0 * K : A + (size_t)m0 * K) + (size_t)(kt) * BK;   \
        char* Lp = (char*)lds + (buf) * 32768 + (isB) * 16384;                        \
        _Pragma("unroll")                                                             \
        for (int i = 0; i < 4; ++i) {                                                 \
            int c = i * 256 + tid;                                                    \
            int row = c >> 3, cl = c & 7;                                             \
            int gc = cl ^ (row & 7);          /* pre-swizzled global chunk */         \
            __builtin_amdgcn_global_load_lds(                                         \
                (const __attribute__((address_space(1))) void*)(Gp + (size_t)row * K + gc * 8), \
                (__attribute__((address_space(3))) void*)(Lp + c * 16), 16, 0, 0);    \
        }                                                                             \
    }
#define STAGE_TILE(buf, kt) STAGE_MAT(buf, kt, 0) STAGE_MAT(buf, kt, 1)

    STAGE_TILE(0, 0);
    STAGE_TILE(1, 1);

    for (int t = 0; t < NT; ++t) {
        if (t == NT - 1) asm volatile("s_waitcnt vmcnt(0)" ::: "memory");
        else             asm volatile("s_waitcnt vmcnt(8)" ::: "memory");
        __builtin_amdgcn_s_barrier();
        const unsigned short* La = lds + (t & 1) * 16384;
        const unsigned short* Lb = La + 8192;
        bf16x8_t af[4][2], bf[4][2];
#pragma unroll
        for (int kkk = 0; kkk < 2; ++kkk) {
#pragma unroll
            for (int mi = 0; mi < 4; ++mi) {
                int row = wr * 64 + mi * 16 + lr;
                int ch = (kkk * 4 + lg) ^ (row & 7);
                af[mi][kkk] = *(const bf16x8_t*)(La + (row * 8 + ch) * 8);
            }
#pragma unroll
            for (int ni = 0; ni < 4; ++ni) {
                int row = wc * 64 + ni * 16 + lr;
                int ch = (kkk * 4 + lg) ^ (row & 7);
                bf[ni][kkk] = *(const bf16x8_t*)(Lb + (row * 8 + ch) * 8);
            }
        }
        asm volatile("s_waitcnt lgkmcnt(0)" ::: "memory");
        __builtin_amdgcn_sched_barrier(0);
        __builtin_amdgcn_s_setprio(1);
#pragma unroll
        for (int kkk = 0; kkk < 2; ++kkk)
#pragma unroll
            for (int mi = 0; mi < 4; ++mi)
#pragma unroll
                for (int ni = 0; ni < 4; ++ni)
                    acc[mi][ni] = __builtin_amdgcn_mfma_f32_16x16x32_bf16(
                        af[mi][kkk], bf[ni][kkk], acc[mi][ni], 0, 0, 0);
        __builtin_amdgcn_s_setprio(0);
        __builtin_amdgcn_s_barrier();
        if (t + 2 < NT) { STAGE_TILE((t & 1), t + 2); }
    }
#undef STAGE_TILE
#undef STAGE_MAT

#pragma unroll
    for (int mi = 0; mi < 4; ++mi) {
#pragma unroll
        for (int i = 0; i < 4; ++i) {
            int m = m0 + wr * 64 + mi * 16 + lg * 4 + i;
            float cf = coef[m];
#pragma unroll
            for (int ni = 0; ni < 4; ++ni) {
                int n = n0 + wc * 64 + ni * 16 + lr;
                size_t idx = (size_t)m * N + n;
                out[idx] = x[idx] + cf * acc[mi][ni][i];
            }
        }
    }
}

// ---------------------------------------------------------------------------
extern "C" void kernel_launch(void* const* d_in, const int* in_sizes, int n_in,
                              void* d_out, int out_size, void* d_ws, size_t ws_size,
                              hipStream_t stream) {
    const float* x  = (const float*)d_in[0];
    const float* q  = (const float*)d_in[1];
    const float* k  = (const float*)d_in[2];
    const float* vv = (const float*)d_in[3];
    const float* W  = (const float*)d_in[4];
    float* out = (float*)d_out;

    const size_t M = (size_t)B_ * S_;           // 16384
    char* ws = (char*)d_ws;
    unsigned short* Ub = (unsigned short*)ws;                      // 32MB
    unsigned short* Wb = (unsigned short*)(ws + M * D_ * 2);       // 2MB
    float* coef = (float*)(ws + M * D_ * 2 + (size_t)D_ * D_ * 2);
    float* rnq  = coef + M;
    float* rnk  = rnq + M;
    size_t needed = M * D_ * 2 + (size_t)D_ * D_ * 2 + 3 * M * 4;
    if (ws_size < needed) return;  // fail visibly (output stays poisoned)

    norms_k<<<dim3(M / 4), dim3(256), 0, stream>>>(q, k, rnq, rnk);
    wconv_k<<<dim3((D_ * D_) / 1024), dim3(256), 0, stream>>>(W, Wb);
    ema_coef_k<<<dim3(B_ * (S_ / TB)), dim3(256), 0, stream>>>(q, k, rnq, rnk, vv, Ub, coef);
    gemm_k<<<dim3((M / BM) * (D_ / BN)), dim3(256), 0, stream>>>(Ub, Wb, coef, x, out);
}